// Round 3
// baseline (3991.914 us; speedup 1.0000x reference)
//
#include <hip/hip_runtime.h>
#include <stdint.h>

typedef __attribute__((ext_vector_type(4))) float floatx4;
typedef __bf16 bf16x8 __attribute__((ext_vector_type(8)));
typedef unsigned short ushort_t;

// float -> bf16 round-to-nearest-even (raw bits)
__device__ __forceinline__ ushort_t f2bf(float f) {
  unsigned u = __float_as_uint(f);
  u += 0x7FFFu + ((u >> 16) & 1u);
  return (ushort_t)(u >> 16);
}

// ---------------- fp32 -> bf16 conversion (vectorized) ----------------
__global__ void cvt_f32_bf16(const float* __restrict__ src,
                             ushort_t* __restrict__ dst, long n) {
  long i = ((long)blockIdx.x * 256 + threadIdx.x) * 4;
  if (i >= n) return;
  float4 v = *(const float4*)(src + i);
  ushort4 o;
  o.x = f2bf(v.x); o.y = f2bf(v.y); o.z = f2bf(v.z); o.w = f2bf(v.w);
  *(ushort4*)(dst + i) = o;
}

// ---------------- bf16 GEMM, C = alpha * A * B^T (+bias) ----------------
// A: [M,K] row-major (lda), B: [N,K] row-major (ldb) -- both K-major.
// 128x128 tile, BK=32, 256 threads = 2x2 waves, each wave 64x64 via 4x4 MFMA.
// Staging: register round-trip (bf16x8 global load -> ds_write_b128); no
// global_load_lds this round (crash bisect).
// MODE 0: fp32 C[r*ldc+c]  = alpha*acc
// MODE 1: bf16 C[r*ldc+c]  = alpha*acc
// MODE 2: bf16 transposed write: C[c*ldc + r]  (V^T, single slice)
// MODE 3: fp32 C[r*ldc+c]  = acc + bias[c]
// MODE 4: fp32 C[r*ldc+c] += alpha*acc
template <int MODE>
__global__ __launch_bounds__(256) void gemm_bt(
    const ushort_t* __restrict__ A, const ushort_t* __restrict__ B,
    void* __restrict__ Cbase, const float* __restrict__ bias,
    int M, int N, int K, int lda, int ldb, int ldc, float alpha) {
  __shared__ alignas(16) ushort_t sA[128 * 32];
  __shared__ alignas(16) ushort_t sB[128 * 32];

  const int tid  = threadIdx.x;
  const int lane = tid & 63;
  const int wave = tid >> 6;
  const int wm = wave >> 1, wn = wave & 1;
  const int row0 = blockIdx.y * 128;
  const int col0 = blockIdx.x * 128;

  // staging coords: thread t covers rows (t>>2) and 64+(t>>2), k-cols (t&3)*8
  const int srow = tid >> 2;         // 0..63
  const int scol = (tid & 3) * 8;    // 0,8,16,24

  const floatx4 zero4 = {0.f, 0.f, 0.f, 0.f};
  floatx4 acc[4][4];
#pragma unroll
  for (int i = 0; i < 4; ++i)
#pragma unroll
    for (int j = 0; j < 4; ++j) acc[i][j] = zero4;

  const int fr = lane & 15;   // m (A) / n (B) index within 16
  const int kq = lane >> 4;   // k-quad

  const ushort_t* Ar0 = A + (long)(row0 + srow) * lda + scol;
  const ushort_t* Ar1 = A + (long)(row0 + 64 + srow) * lda + scol;
  const ushort_t* Br0 = B + (long)(col0 + srow) * ldb + scol;
  const ushort_t* Br1 = B + (long)(col0 + 64 + srow) * ldb + scol;

  for (int k0 = 0; k0 < K; k0 += 32) {
    bf16x8 ga0 = *(const bf16x8*)(Ar0 + k0);
    bf16x8 ga1 = *(const bf16x8*)(Ar1 + k0);
    bf16x8 gb0 = *(const bf16x8*)(Br0 + k0);
    bf16x8 gb1 = *(const bf16x8*)(Br1 + k0);
    __syncthreads();  // previous iteration's LDS reads complete
    *(bf16x8*)&sA[srow * 32 + scol] = ga0;
    *(bf16x8*)&sA[(64 + srow) * 32 + scol] = ga1;
    *(bf16x8*)&sB[srow * 32 + scol] = gb0;
    *(bf16x8*)&sB[(64 + srow) * 32 + scol] = gb1;
    __syncthreads();  // writes visible

    bf16x8 af[4], bfr[4];
#pragma unroll
    for (int i = 0; i < 4; ++i)
      af[i] = *(const bf16x8*)&sA[(wm * 64 + i * 16 + fr) * 32 + kq * 8];
#pragma unroll
    for (int j = 0; j < 4; ++j)
      bfr[j] = *(const bf16x8*)&sB[(wn * 64 + j * 16 + fr) * 32 + kq * 8];
#pragma unroll
    for (int i = 0; i < 4; ++i)
#pragma unroll
      for (int j = 0; j < 4; ++j)
        acc[i][j] = __builtin_amdgcn_mfma_f32_16x16x32_bf16(af[i], bfr[j],
                                                            acc[i][j], 0, 0, 0);
  }

  // C/D layout: col = lane&15, row = (lane>>4)*4 + reg   [verified m89/m91]
  const int ccol  = lane & 15;
  const int crow4 = (lane >> 4) * 4;

  if (MODE == 0 || MODE == 3 || MODE == 4) {
    float* C = (float*)Cbase;
#pragma unroll
    for (int i = 0; i < 4; ++i) {
      const int rbase = row0 + wm * 64 + i * 16 + crow4;
#pragma unroll
      for (int j = 0; j < 4; ++j) {
        const int c = col0 + wn * 64 + j * 16 + ccol;
        const float bb = (MODE == 3) ? bias[c] : 0.f;
#pragma unroll
        for (int r = 0; r < 4; ++r) {
          const long idx = (long)(rbase + r) * ldc + c;
          float v;
          if (MODE == 3)      v = acc[i][j][r] + bb;
          else if (MODE == 4) v = C[idx] + alpha * acc[i][j][r];
          else                v = alpha * acc[i][j][r];
          C[idx] = v;
        }
      }
    }
  } else if (MODE == 1) {
    ushort_t* C = (ushort_t*)Cbase;
#pragma unroll
    for (int i = 0; i < 4; ++i) {
      const int rbase = row0 + wm * 64 + i * 16 + crow4;
#pragma unroll
      for (int j = 0; j < 4; ++j) {
        const int c = col0 + wn * 64 + j * 16 + ccol;
#pragma unroll
        for (int r = 0; r < 4; ++r)
          C[(long)(rbase + r) * ldc + c] = f2bf(alpha * acc[i][j][r]);
      }
    }
  } else {  // MODE 2: transposed: C[c*ldc + r]
    ushort_t* C = (ushort_t*)Cbase;
#pragma unroll
    for (int i = 0; i < 4; ++i) {
      const int rbase = row0 + wm * 64 + i * 16 + crow4;
#pragma unroll
      for (int j = 0; j < 4; ++j) {
        const int c = col0 + wn * 64 + j * 16 + ccol;
#pragma unroll
        for (int r = 0; r < 4; ++r)
          C[(long)c * ldc + (rbase + r)] = f2bf(acc[i][j][r]);
      }
    }
  }
}

// ---------------- column softmax (over query axis n), one slice ----------------
// S: [2048 n][2048 m] fp32. For each m: softmax over n. w: [2048 n][2048 m] bf16.
// Block 256 = 32 cols x 8 n-strips of 256. Grid 64.
__global__ void softmax_cols(const float* __restrict__ S,
                             ushort_t* __restrict__ w) {
  __shared__ float red[8][32];
  const int tx = threadIdx.x & 31;
  const int ty = threadIdx.x >> 5;
  const int m = blockIdx.x * 32 + tx;
  const float* Sm = S + m;
  const int n0 = ty * 256;

  float mx = -3.0e38f;
#pragma unroll 8
  for (int n = n0; n < n0 + 256; ++n) mx = fmaxf(mx, Sm[(long)n * 2048]);
  red[ty][tx] = mx;
  __syncthreads();
  mx = red[0][tx];
#pragma unroll
  for (int s = 1; s < 8; ++s) mx = fmaxf(mx, red[s][tx]);
  __syncthreads();

  float sum = 0.f;
#pragma unroll 8
  for (int n = n0; n < n0 + 256; ++n) sum += __expf(Sm[(long)n * 2048] - mx);
  red[ty][tx] = sum;
  __syncthreads();
  sum = red[0][tx];
#pragma unroll
  for (int s = 1; s < 8; ++s) sum += red[s][tx];
  const float inv = 1.f / sum;

  ushort_t* wm_ = w + m;
#pragma unroll 4
  for (int n = n0; n < n0 + 256; ++n)
    wm_[(long)n * 2048] = f2bf(__expf(Sm[(long)n * 2048] - mx) * inv);
}

extern "C" void kernel_launch(void* const* d_in, const int* in_sizes, int n_in,
                              void* d_out, int out_size, void* d_ws,
                              size_t ws_size, hipStream_t stream) {
  const float* x   = (const float*)d_in[0];
  const float* Wq  = (const float*)d_in[1];
  const float* Wk  = (const float*)d_in[2];
  const float* Wv  = (const float*)d_in[3];
  const float* fcw = (const float*)d_in[4];
  const float* fcb = (const float*)d_in[5];
  float* out = (float*)d_out;

  // ---- workspace layout: 104 MiB total ----
  char* ws = (char*)d_ws;
  size_t off = 0;
  auto alloc = [&](size_t bytes) {
    char* p = ws + off;
    off += (bytes + 255) & ~(size_t)255;
    return p;
  };
  const long SL = 4194304L;  // 2048*2048 elements per slice
  ushort_t* xb   = (ushort_t*)alloc(33554432);  // x bf16 [8192][2048]
  ushort_t* fcwb = (ushort_t*)alloc(8388608);   // fc_w bf16
  char* loop0 = ws + off;                       // per-(h,b) region, 67.1 MB
  ushort_t* Wqh  = (ushort_t*)alloc(8388608);   // Wq[h] bf16
  ushort_t* Wkh  = (ushort_t*)alloc(8388608);
  ushort_t* Wvh  = (ushort_t*)alloc(8388608);
  ushort_t* Qhb  = (ushort_t*)alloc(8388608);   // Q[h,b] bf16 [2048][2048]
  ushort_t* Khb  = (ushort_t*)alloc(8388608);
  ushort_t* Vthb = (ushort_t*)alloc(8388608);   // V[h,b]^T bf16 [d][m]
  float*    S    = (float*)alloc(16777216);     // scores fp32 [2048][2048]
  ushort_t* wchb = Qhb;          // softmax weights overlay (Q dead by then)
  ushort_t* meanb = (ushort_t*)loop0;  // bf16 mean overlay, after loops
  float* mean32 = out;           // fp32 head-sum accumulator lives in d_out

  const dim3 blk(256);
  const float scale = 0.022097086912079608f;  // 1/sqrt(2048)

  // input conversions
  cvt_f32_bf16<<<16384, blk, 0, stream>>>(x, xb, 16777216L);
  cvt_f32_bf16<<<4096, blk, 0, stream>>>(fcw, fcwb, 4194304L);

  for (int h = 0; h < 3; ++h) {
    cvt_f32_bf16<<<4096, blk, 0, stream>>>(Wq + h * SL, Wqh, SL);
    cvt_f32_bf16<<<4096, blk, 0, stream>>>(Wk + h * SL, Wkh, SL);
    cvt_f32_bf16<<<4096, blk, 0, stream>>>(Wv + h * SL, Wvh, SL);

    for (int b = 0; b < 4; ++b) {
      const ushort_t* xbb = xb + b * SL;
      // projections (M=N=K=2048)
      gemm_bt<1><<<dim3(16, 16), blk, 0, stream>>>(
          xbb, Wqh, Qhb, nullptr, 2048, 2048, 2048, 2048, 2048, 2048, 1.0f);
      gemm_bt<1><<<dim3(16, 16), blk, 0, stream>>>(
          xbb, Wkh, Khb, nullptr, 2048, 2048, 2048, 2048, 2048, 2048, 1.0f);
      gemm_bt<2><<<dim3(16, 16), blk, 0, stream>>>(
          xbb, Wvh, Vthb, nullptr, 2048, 2048, 2048, 2048, 2048, 2048, 1.0f);
      // scores S = scale * Q @ K^T
      gemm_bt<0><<<dim3(16, 16), blk, 0, stream>>>(
          Qhb, Khb, S, nullptr, 2048, 2048, 2048, 2048, 2048, 2048, scale);
      // column softmax (query axis) -> wchb (overlays Qhb)
      softmax_cols<<<64, blk, 0, stream>>>(S, wchb);
      // mean32[b] (+)= (1/3) * wchb @ Vthb^T
      if (h == 0)
        gemm_bt<0><<<dim3(16, 16), blk, 0, stream>>>(
            wchb, Vthb, mean32 + b * SL, nullptr,
            2048, 2048, 2048, 2048, 2048, 2048, 1.0f / 3.0f);
      else
        gemm_bt<4><<<dim3(16, 16), blk, 0, stream>>>(
            wchb, Vthb, mean32 + b * SL, nullptr,
            2048, 2048, 2048, 2048, 2048, 2048, 1.0f / 3.0f);
    }
  }

  // mean (in d_out) -> bf16 in ws, then out = mean @ fc_w^T + fc_b
  cvt_f32_bf16<<<16384, blk, 0, stream>>>(mean32, meanb, 16777216L);
  gemm_bt<3><<<dim3(16, 64), blk, 0, stream>>>(
      meanb, fcwb, out, fcb, 8192, 2048, 2048, 2048, 2048, 2048, 1.0f);
}

// Round 4
// 2307.745 us; speedup vs baseline: 1.7298x; 1.7298x over previous
//
#include <hip/hip_runtime.h>
#include <stdint.h>

typedef __attribute__((ext_vector_type(4))) float floatx4;
typedef __bf16 bf16x8 __attribute__((ext_vector_type(8)));
typedef unsigned short ushort_t;

// float -> bf16 round-to-nearest-even (raw bits)
__device__ __forceinline__ ushort_t f2bf(float f) {
  unsigned u = __float_as_uint(f);
  u += 0x7FFFu + ((u >> 16) & 1u);
  return (ushort_t)(u >> 16);
}

// async global->LDS, 16B per lane. LDS dest is wave-uniform base + lane*16.
__device__ __forceinline__ void gl_lds16(const void* g, void* l) {
  __builtin_amdgcn_global_load_lds(
      (__attribute__((address_space(1))) void*)g,
      (__attribute__((address_space(3))) void*)l, 16, 0, 0);
}

// ---------------- fp32 -> bf16 conversion (vectorized) ----------------
__global__ void cvt_f32_bf16(const float* __restrict__ src,
                             ushort_t* __restrict__ dst, long n) {
  long i = ((long)blockIdx.x * 256 + threadIdx.x) * 4;
  if (i >= n) return;
  float4 v = *(const float4*)(src + i);
  ushort4 o;
  o.x = f2bf(v.x); o.y = f2bf(v.y); o.z = f2bf(v.z); o.w = f2bf(v.w);
  *(ushort4*)(dst + i) = o;
}

// XCD supertile swizzle: flat ids round-robin XCDs (%8); give each XCD a 4x8
// patch of a 16x16 supertile so its L2 working set is ~6MB not full-B.
// Identity when grid dims aren't multiples of 16.
__device__ __forceinline__ void swz(int& bx, int& by) {
  const int gx = gridDim.x, gy = gridDim.y;
  if ((gx & 15) == 0 && (gy & 15) == 0) {
    const int flat = blockIdx.x + gx * blockIdx.y;
    const int super = flat >> 8, within = flat & 255;
    const int xcd = within & 7, slot = within >> 3;
    const int prow = ((xcd >> 1) << 2) | (slot >> 3);  // 0..15
    const int pcol = ((xcd & 1) << 3) | (slot & 7);    // 0..15
    const int supercols = gx >> 4;
    bx = (super % supercols) * 16 + pcol;
    by = (super / supercols) * 16 + prow;
  } else {
    bx = blockIdx.x;
    by = blockIdx.y;
  }
}

// ---------------- bf16 GEMM, C = alpha * A * B^T (+bias) ----------------
// A: [M,K] row-major (lda), B: [N,K] row-major (ldb) -- both K-major.
// 128x128 tile, BK=32, 256 thr = 2x2 waves, 4x4 MFMA acc/wave. m97 staging:
// global_load_lds width=16.
// MODE 0: fp32 C[r*ldc+c]  = alpha*acc        (z-strided)
// MODE 1: bf16 C[r*ldc+c]  = alpha*acc        (z-strided)
// MODE 3: fp32 C[r*ldc+c]  = acc + bias[c]
// MODE 4: fp32 C[r*ldc+c] += alpha*acc        (z-strided)
// MODE 5: fused QKV routing, QS=strideC elements per slab:
//         c<2048:  C[r*2048+c]                      (Q [b][n][d])
//         c<4096:  C[QS + r*2048 + (c-2048)]        (K [b][n][d])
//         else:    C[2*QS + (r>>11)*4194304 + (c-4096)*2048 + (r&2047)] (V^T [b][d][m])
template <int MODE>
__global__ __launch_bounds__(256) void gemm_bt(
    const ushort_t* __restrict__ Abase, const ushort_t* __restrict__ Bbase,
    void* __restrict__ Cbase, const float* __restrict__ bias,
    int M, int N, int K, int lda, int ldb, int ldc,
    long strideA, long strideB, long strideC, float alpha) {
  __shared__ alignas(16) ushort_t sA[128 * 32];
  __shared__ alignas(16) ushort_t sB[128 * 32];

  const int z = blockIdx.z;
  const ushort_t* A = Abase + (long)z * strideA;
  const ushort_t* B = Bbase + (long)z * strideB;

  int bx, by;
  swz(bx, by);
  const int row0 = by * 128;
  const int col0 = bx * 128;

  const int tid  = threadIdx.x;
  const int lane = tid & 63;
  const int wave = tid >> 6;
  const int wm = wave >> 1, wn = wave & 1;

  // staging: per wave, 2 chunks of 16 rows; lane l -> row l>>2, k-col (l&3)*8.
  // LDS byte offset inside chunk = 16*lane (matches gl_lds16 scatter).
  const int srow = lane >> 2;
  const int scol = (lane & 3) * 8;

  const floatx4 zero4 = {0.f, 0.f, 0.f, 0.f};
  floatx4 acc[4][4];
#pragma unroll
  for (int i = 0; i < 4; ++i)
#pragma unroll
    for (int j = 0; j < 4; ++j) acc[i][j] = zero4;

  const int fr = lane & 15;   // m (A) / n (B) index within 16
  const int kq = lane >> 4;   // k-quad

  for (int k0 = 0; k0 < K; k0 += 32) {
#pragma unroll
    for (int c = 0; c < 2; ++c) {
      const int chunk = wave * 2 + c;  // 0..7, wave-uniform
      gl_lds16(A + (long)(row0 + chunk * 16 + srow) * lda + k0 + scol,
               &sA[chunk * 512]);
      gl_lds16(B + (long)(col0 + chunk * 16 + srow) * ldb + k0 + scol,
               &sB[chunk * 512]);
    }
    __syncthreads();  // drains vmcnt (global_load_lds) + barrier

    bf16x8 af[4], bfr[4];
#pragma unroll
    for (int i = 0; i < 4; ++i)
      af[i] = *(const bf16x8*)&sA[(wm * 64 + i * 16 + fr) * 32 + kq * 8];
#pragma unroll
    for (int j = 0; j < 4; ++j)
      bfr[j] = *(const bf16x8*)&sB[(wn * 64 + j * 16 + fr) * 32 + kq * 8];
#pragma unroll
    for (int i = 0; i < 4; ++i)
#pragma unroll
      for (int j = 0; j < 4; ++j)
        acc[i][j] = __builtin_amdgcn_mfma_f32_16x16x32_bf16(af[i], bfr[j],
                                                            acc[i][j], 0, 0, 0);
    __syncthreads();
  }

  // C/D layout: col = lane&15, row = (lane>>4)*4 + reg   [verified m89/m91]
  const int ccol  = lane & 15;
  const int crow4 = (lane >> 4) * 4;

  if (MODE == 0 || MODE == 3 || MODE == 4) {
    float* C = (float*)Cbase + (long)z * strideC;
#pragma unroll
    for (int i = 0; i < 4; ++i) {
      const int rbase = row0 + wm * 64 + i * 16 + crow4;
#pragma unroll
      for (int j = 0; j < 4; ++j) {
        const int c = col0 + wn * 64 + j * 16 + ccol;
        const float bb = (MODE == 3) ? bias[c] : 0.f;
#pragma unroll
        for (int r = 0; r < 4; ++r) {
          const long idx = (long)(rbase + r) * ldc + c;
          float v;
          if (MODE == 3)      v = acc[i][j][r] + bb;
          else if (MODE == 4) v = C[idx] + alpha * acc[i][j][r];
          else                v = alpha * acc[i][j][r];
          C[idx] = v;
        }
      }
    }
  } else if (MODE == 1) {
    ushort_t* C = (ushort_t*)Cbase + (long)z * strideC;
#pragma unroll
    for (int i = 0; i < 4; ++i) {
      const int rbase = row0 + wm * 64 + i * 16 + crow4;
#pragma unroll
      for (int j = 0; j < 4; ++j) {
        const int c = col0 + wn * 64 + j * 16 + ccol;
#pragma unroll
        for (int r = 0; r < 4; ++r)
          C[(long)(rbase + r) * ldc + c] = f2bf(alpha * acc[i][j][r]);
      }
    }
  } else {  // MODE 5
    ushort_t* C = (ushort_t*)Cbase;
    const long QS = strideC;
#pragma unroll
    for (int i = 0; i < 4; ++i) {
      const int rbase = row0 + wm * 64 + i * 16 + crow4;
#pragma unroll
      for (int j = 0; j < 4; ++j) {
        const int c = col0 + wn * 64 + j * 16 + ccol;
#pragma unroll
        for (int r = 0; r < 4; ++r) {
          const int rr = rbase + r;
          const ushort_t v = f2bf(acc[i][j][r]);
          if (c < 2048)
            C[(long)rr * 2048 + c] = v;
          else if (c < 4096)
            C[QS + (long)rr * 2048 + (c - 2048)] = v;
          else
            C[2 * QS + (long)(rr >> 11) * 4194304 + (long)(c - 4096) * 2048 +
              (rr & 2047)] = v;
        }
      }
    }
  }
}

// ---------------- online column softmax (over query axis n) ----------------
// S,w: [nz][2048 n][2048 m]; per (z,m): softmax over n. 2 passes over S.
// Block 256 = 32 cols x 8 n-strips of 256. Grid (64, nz).
__global__ void softmax_cols(const float* __restrict__ Sbase,
                             ushort_t* __restrict__ wbase) {
  __shared__ float rmx[8][32], rsum[8][32];
  const long zoff = (long)blockIdx.y * 4194304;
  const int tx = threadIdx.x & 31;
  const int ty = threadIdx.x >> 5;
  const int m = blockIdx.x * 32 + tx;
  const float* Sm = Sbase + zoff + m;
  const int n0 = ty * 256;

  float mx = -3.0e38f, sum = 0.f;
#pragma unroll 4
  for (int n = n0; n < n0 + 256; ++n) {
    const float v = Sm[(long)n * 2048];
    if (v > mx) {
      sum = sum * __expf(mx - v) + 1.f;
      mx = v;
    } else {
      sum += __expf(v - mx);
    }
  }
  rmx[ty][tx] = mx;
  rsum[ty][tx] = sum;
  __syncthreads();
  float gm = rmx[0][tx];
#pragma unroll
  for (int s = 1; s < 8; ++s) gm = fmaxf(gm, rmx[s][tx]);
  float gs = 0.f;
#pragma unroll
  for (int s = 0; s < 8; ++s) gs += rsum[s][tx] * __expf(rmx[s][tx] - gm);
  const float inv = 1.f / gs;

  ushort_t* wm_ = wbase + zoff + m;
#pragma unroll 4
  for (int n = n0; n < n0 + 256; ++n)
    wm_[(long)n * 2048] = f2bf(__expf(Sm[(long)n * 2048] - gm) * inv);
}

extern "C" void kernel_launch(void* const* d_in, const int* in_sizes, int n_in,
                              void* d_out, int out_size, void* d_ws,
                              size_t ws_size, hipStream_t stream) {
  const float* x   = (const float*)d_in[0];
  const float* Wq  = (const float*)d_in[1];
  const float* Wk  = (const float*)d_in[2];
  const float* Wv  = (const float*)d_in[3];
  const float* fcw = (const float*)d_in[4];
  const float* fcb = (const float*)d_in[5];
  float* out = (float*)d_out;

  char* ws = (char*)d_ws;
  size_t off = 0;
  auto alloc = [&](size_t bytes) {
    char* p = ws + off;
    off += (bytes + 255) & ~(size_t)255;
    return p;
  };
  const long SL = 4194304L;  // 2048*2048 elements
  const dim3 blk(256);
  const float scale = 0.022097086912079608f;  // 1/sqrt(2048)

  // persistent
  ushort_t* xb   = (ushort_t*)alloc(33554432);  // x bf16 [8192][2048]
  ushort_t* fcwb = (ushort_t*)alloc(8388608);   // fc_w bf16
  float* mean32 = out;                          // fp32 head-sum accumulator in d_out
  char* loop0 = ws + off;

  cvt_f32_bf16<<<16384, blk, 0, stream>>>(x, xb, 16777216L);
  cvt_f32_bf16<<<4096, blk, 0, stream>>>(fcw, fcwb, 4194304L);

  // Layout A (batched over all b) needs 234,881,024 bytes total.
  const bool big = ws_size >= 234881024ULL;

  if (big) {
    ushort_t* Wcat = (ushort_t*)alloc(25165824);   // [6144][2048] bf16
    ushort_t* Qh   = (ushort_t*)alloc(33554432);   // [4][2048][2048]
    ushort_t* Kh   = (ushort_t*)alloc(33554432);   // contiguous after Qh
    ushort_t* Vth  = (ushort_t*)alloc(33554432);   // [4][2048 d][2048 m]
    float*    S    = (float*)alloc(67108864);      // [4][2048][2048] fp32
    ushort_t* wc   = Qh;                           // overlay (Q dead post-scores)
    (void)Kh; (void)Vth;

    for (int h = 0; h < 3; ++h) {
      cvt_f32_bf16<<<4096, blk, 0, stream>>>(Wq + h * SL, Wcat, SL);
      cvt_f32_bf16<<<4096, blk, 0, stream>>>(Wk + h * SL, Wcat + SL, SL);
      cvt_f32_bf16<<<4096, blk, 0, stream>>>(Wv + h * SL, Wcat + 2 * SL, SL);

      // fused QKV projection: M=8192, N=6144; QS slab = 16777216 elements
      gemm_bt<5><<<dim3(48, 64), blk, 0, stream>>>(
          xb, Wcat, Qh, nullptr, 8192, 6144, 2048, 2048, 2048, 2048,
          0L, 0L, 16777216L, 1.0f);
      // scores, batched z=b
      gemm_bt<0><<<dim3(16, 16, 4), blk, 0, stream>>>(
          Qh, Qh + 16777216L, S, nullptr, 2048, 2048, 2048, 2048, 2048, 2048,
          SL, SL, SL, scale);
      softmax_cols<<<dim3(64, 4), blk, 0, stream>>>(S, wc);
      // mean32[b] (+)= (1/3) * wc[b] @ Vth[b]^T
      if (h == 0)
        gemm_bt<0><<<dim3(16, 16, 4), blk, 0, stream>>>(
            wc, Qh + 33554432L, mean32, nullptr, 2048, 2048, 2048,
            2048, 2048, 2048, SL, SL, SL, 1.0f / 3.0f);
      else
        gemm_bt<4><<<dim3(16, 16, 4), blk, 0, stream>>>(
            wc, Qh + 33554432L, mean32, nullptr, 2048, 2048, 2048,
            2048, 2048, 2048, SL, SL, SL, 1.0f / 3.0f);
    }
  } else {
    // compact: exact round-3 footprint (109,051,904 bytes; proven safe)
    ushort_t* Wqh  = (ushort_t*)alloc(8388608);  // [2048][2048] -+
    ushort_t* Wkh  = (ushort_t*)alloc(8388608);  //               | contiguous
    ushort_t* Wvh  = (ushort_t*)alloc(8388608);  //              -+ = [6144][2048]
    ushort_t* Qhb  = (ushort_t*)alloc(8388608);  // [2048][2048] -+
    ushort_t* Khb  = (ushort_t*)alloc(8388608);  //               | contiguous
    ushort_t* Vthb = (ushort_t*)alloc(8388608);  //              -+
    float*    S    = (float*)alloc(16777216);    // [2048][2048] fp32
    ushort_t* wchb = Qhb;                        // overlay
    (void)Wkh; (void)Wvh; (void)Khb; (void)Vthb;

    for (int h = 0; h < 3; ++h) {
      cvt_f32_bf16<<<4096, blk, 0, stream>>>(Wq + h * SL, Wqh, SL);
      cvt_f32_bf16<<<4096, blk, 0, stream>>>(Wk + h * SL, Wqh + SL, SL);
      cvt_f32_bf16<<<4096, blk, 0, stream>>>(Wv + h * SL, Wqh + 2 * SL, SL);

      for (int b = 0; b < 4; ++b) {
        const ushort_t* xbb = xb + b * SL;
        // fused QKV projection: M=2048, N=6144; QS slab = 4194304 elements
        gemm_bt<5><<<dim3(48, 16), blk, 0, stream>>>(
            xbb, Wqh, Qhb, nullptr, 2048, 6144, 2048, 2048, 2048, 2048,
            0L, 0L, 4194304L, 1.0f);
        gemm_bt<0><<<dim3(16, 16), blk, 0, stream>>>(
            Qhb, Qhb + SL, S, nullptr, 2048, 2048, 2048, 2048, 2048, 2048,
            0L, 0L, 0L, scale);
        softmax_cols<<<dim3(64, 1), blk, 0, stream>>>(S, wchb);
        if (h == 0)
          gemm_bt<0><<<dim3(16, 16), blk, 0, stream>>>(
              wchb, Qhb + 2 * SL, mean32 + b * SL, nullptr, 2048, 2048, 2048,
              2048, 2048, 2048, 0L, 0L, 0L, 1.0f / 3.0f);
        else
          gemm_bt<4><<<dim3(16, 16), blk, 0, stream>>>(
              wchb, Qhb + 2 * SL, mean32 + b * SL, nullptr, 2048, 2048, 2048,
              2048, 2048, 2048, 0L, 0L, 0L, 1.0f / 3.0f);
      }
    }
  }

  // mean (in d_out) -> bf16 overlay in loop region, then out = mean@fc_w^T + fc_b
  ushort_t* meanb = (ushort_t*)loop0;
  cvt_f32_bf16<<<16384, blk, 0, stream>>>(mean32, meanb, 16777216L);
  gemm_bt<3><<<dim3(16, 64), blk, 0, stream>>>(
      meanb, fcwb, out, fcb, 8192, 2048, 2048, 2048, 2048, 2048,
      0L, 0L, 0L, 1.0f);
}